// Round 15
// baseline (11.382 us; speedup 1.0000x reference)
//
#include <hip/hip_runtime.h>

#define TPB  512           // 8 waves; 8 receivers per block; 2 blocks/CU resident
#define RPB  8
#define NMAX 4096          // max tokens (test: N=4096)
#define MAXC 1024          // max cells (gs <= 32; test gs = 32); gs >= 4 for wrap
#define CAP  16            // bucket capacity; cnt>CAP cells -> exact fallback scan

__device__ __forceinline__ float fpow_pos(float x, float p) {
    // x >= 0; pow via hardware log2/exp2. x==0 -> log2=-inf -> exp2(-inf)=0 (p>0).
    return __builtin_exp2f(p * __builtin_log2f(x));
}

// ONE node. R15: 512-thr blocks, 2 resident/CU — co-resident blocks hide each
// other's phase-1 load/atomic latency and barrier stalls (R14's 1024-thr
// 1-block/CU layout left the CU idle there; kernel was latency-bound, not
// issue-bound). Receiver setup hoisted before the first barrier.
__global__ __launch_bounds__(TPB) void gwave_one(
    const float* __restrict__ ell, const float* __restrict__ theta,
    const float* __restrict__ fs, const float* __restrict__ mass,
    const unsigned char* __restrict__ frozen,
    const int* __restrict__ gsize_p, int n,
    float* __restrict__ out)
{
    __shared__ int s_cnt[MAXC];                    //  4 KB
    __shared__ unsigned short s_buck[MAXC][CAP];   // 32 KB (token ids)

    const float PHI       = 1.61803398875f;
    const float INV_PHI   = 0.61803398875f;
    const float ONE_P_PHI = 2.61803398875f;
    const float TAU  = 6.2831855f;                 // float32(2*pi)
    const float PI_F = 3.14159274f;                // float32(pi)
    const float EPS  = 1e-10f;

    const int tid  = threadIdx.x;
    const int lane = tid & 63;
    const int w    = tid >> 6;
    const int gs = *gsize_p;
    const int C = gs * gs;                         // <= MAXC
    const bool pow2   = (gs & (gs - 1)) == 0;
    const float mule  = (float)gs * 0.5f;          // 1/cw_ell, exact iff pow2
    const float cw_ell = 2.0f / (float)gs;
    const float cw_th  = TAU  / (float)gs;

    // cell coords (bit-exact vs reference for all inputs)
    auto cell_ce = [&](float e) -> int {
        const float q = pow2 ? e * mule : e / cw_ell;
        return min(max((int)floorf(q), 0), gs - 1);
    };
    auto cell_ct = [&](float t) -> int {
        float tw = t;
        if (!(t >= 0.f && t < TAU))                // rare path: exact floor-mod
            tw = t - floorf(t / TAU) * TAU;
        return min(max((int)floorf(tw / cw_th), 0), gs - 1);
    };

    // ---- zero counters (no barrier yet) ----
    for (int c = tid; c < C; c += TPB) s_cnt[c] = 0;

    // ---- receiver setup, hoisted pre-barrier (register-only, no LDS dep) ----
    const int i = blockIdx.x * RPB + w;            // wave-uniform receiver
    const int k    = lane / 7;                     // 0..9 (lane 63: k=9, idle)
    const int slot = lane - k * 7;                 // 0..6
    bool  act = false;
    float e_i = 0.f, t_i = 0.f, f_i = 0.f, m_i = 1.f, tp = 0.f;
    int   c_k = -1;
    if (i < n && !frozen[i]) {
        act = true;
        e_i = ell[i]; t_i = theta[i]; f_i = fs[i]; m_i = mass[i];
        tp = PI_F - t_i;
        const int ce_i = cell_ce(e_i);
        const int ct_i = cell_ct(t_i);
        if (k < 9) {
            const int kdiv = k / 3;
            const int ce = ce_i + kdiv - 1;                    // ell: no wrap
            if (ce >= 0 && ce < gs) {
                int ct = ct_i + (k - kdiv * 3) - 1;            // theta: wraps
                ct += (ct < 0)   ? gs : 0;
                ct -= (ct >= gs) ? gs : 0;
                c_k = ce * gs + ct;
            }
        }
    }
    __syncthreads();                               // counters zeroed

    // ---- Phase 1: bucket all tokens (8/thread at n=4096, vectorized) ----
    const int n4 = n >> 2;
    for (int b = tid; b < n4; b += TPB) {
        const float4 e4 = ((const float4*)ell)[b];
        const float4 t4 = ((const float4*)theta)[b];
        const uchar4 z4 = ((const uchar4*)frozen)[b];
        const float ee[4] = {e4.x, e4.y, e4.z, e4.w};
        const float tt[4] = {t4.x, t4.y, t4.z, t4.w};
        const unsigned char zz[4] = {z4.x, z4.y, z4.z, z4.w};
        #pragma unroll
        for (int m = 0; m < 4; ++m) {
            if (!zz[m]) {
                const int c = cell_ce(ee[m]) * gs + cell_ct(tt[m]);
                const int pos = atomicAdd(&s_cnt[c], 1);
                if (pos < CAP) s_buck[c][pos] = (unsigned short)((b << 2) + m);
            }
        }
    }
    for (int r = (n4 << 2) + tid; r < n; r += TPB) {          // scalar tail
        if (!frozen[r]) {
            const int c = cell_ce(ell[r]) * gs + cell_ct(theta[r]);
            const int pos = atomicAdd(&s_cnt[c], 1);
            if (pos < CAP) s_buck[c][pos] = (unsigned short)r;
        }
    }
    __syncthreads();                               // buckets ready

    // ---- Phase 2: one wave per receiver ----
    if (i >= n) return;                            // after all barriers

    float Fe = 0.f, Ft = 0.f;
    if (act) {                                     // act is wave-uniform
        // candidate chain (id != i checked by caller)
        auto chain = [&](int id) {
            const float dl = ell[id] - e_i;
            // jnp.mod(dtheta+pi, tau)-pi via predicated wrap: x in (-pi,3pi),
            // so +-TAU correction matches floor-mod bit-for-bit.
            float x = theta[id] + tp;
            x += (x < 0.f)  ? TAU : 0.f;
            x -= (x >= TAU) ? TAU : 0.f;
            const float dt = x - PI_F;
            const float inner = fpow_pos(fabsf(dl), PHI)
                              + fpow_pos(fabsf(dt), PHI);
            const float dL = fpow_pos(inner, INV_PHI) + EPS;
            const float fm = __fdividef(f_i * fs[id],
                                fpow_pos(dL, ONE_P_PHI) * m_i + EPS);
            const float ww = fm * __fdividef(1.f, dL);
            Fe += ww * dl;
            Ft += ww * dt;
        };

        const int  cnt        = (c_k >= 0) ? s_cnt[c_k] : 0;
        const bool cell_ok    = (c_k >= 0);
        const bool use_bucket = cell_ok && (cnt <= CAP);

        // bucket passes: slots [0,7), then ballot-guarded [7,14), [14,16)
        #pragma unroll
        for (int base = 0; base < CAP; base += 7) {
            if (base > 0) {
                const unsigned long long need =
                    __ballot(use_bucket && slot == 0 && cnt > base);
                if (!need) break;                             // wave-uniform
            }
            const int s2 = base + slot;
            if (use_bucket && s2 < cnt) {                     // s2 < cnt <= 16
                const int id = s_buck[c_k][s2];
                if (id != i) chain(id);
            }
        }

        // exact fallback for overflowed cells (cnt > CAP): whole-cell rescan
        const unsigned long long oflow =
            __ballot(cell_ok && slot == 0 && cnt > CAP);
        if (oflow) {                                          // ~never taken
            for (int kk = 0; kk < 9; ++kk) {
                const int src  = kk * 7;
                const int cc   = __shfl(c_k, src);
                const int ccnt = __shfl(cnt, src);
                if (cc >= 0 && ccnt > CAP) {
                    for (int q = lane; q < n; q += 64) {
                        if (q != i && !frozen[q]) {
                            const int cq = cell_ce(ell[q]) * gs
                                         + cell_ct(theta[q]);
                            if (cq == cc) chain(q);
                        }
                    }
                }
            }
        }
    }

    // 64-lane butterfly reduce
    Fe += __shfl_xor(Fe, 1);
    Ft += __shfl_xor(Ft, 1);
    Fe += __shfl_xor(Fe, 2);
    Ft += __shfl_xor(Ft, 2);
    Fe += __shfl_xor(Fe, 4);
    Ft += __shfl_xor(Ft, 4);
    Fe += __shfl_xor(Fe, 8);
    Ft += __shfl_xor(Ft, 8);
    Fe += __shfl_xor(Fe, 16);
    Ft += __shfl_xor(Ft, 16);
    Fe += __shfl_xor(Fe, 32);
    Ft += __shfl_xor(Ft, 32);

    if (lane == 0) {                               // frozen receivers store 0
        out[i]     = Fe;
        out[n + i] = Ft;
    }
}

extern "C" void kernel_launch(void* const* d_in, const int* in_sizes, int n_in,
                              void* d_out, int out_size, void* d_ws, size_t ws_size,
                              hipStream_t stream) {
    const float* ell   = (const float*)d_in[0];
    const float* theta = (const float*)d_in[1];
    const float* fs    = (const float*)d_in[2];
    const float* mass  = (const float*)d_in[3];
    const unsigned char* frozen = (const unsigned char*)d_in[4];
    const int* gsize   = (const int*)d_in[5];
    float* out = (float*)d_out;
    const int n = in_sizes[0];                // assumed <= NMAX (test: 4096)

    const int blocks = (n + RPB - 1) / RPB;   // 512 at n=4096 — 2 per CU
    gwave_one<<<blocks, TPB, 0, stream>>>(
        ell, theta, fs, mass, frozen, gsize, n, out);
}

// Round 16
// 10.861 us; speedup vs baseline: 1.0480x; 1.0480x over previous
//
#include <hip/hip_runtime.h>

#define TPB  1024          // 16 waves; 16 receivers per block; 1 block/CU
#define RPB  16
#define NMAX 4096          // max tokens (test: N=4096)
#define MAXC 1024          // max cells (gs <= 32; test gs = 32); gs >= 4 for wrap
#define CAP  16            // bucket capacity; cnt>CAP cells -> exact fallback scan

__device__ __forceinline__ float fpow_pos(float x, float p) {
    // x >= 0; pow via hardware log2/exp2. x==0 -> log2=-inf -> exp2(-inf)=0 (p>0).
    return __builtin_exp2f(p * __builtin_log2f(x));
}

// ONE node, R14 shape (TPB=1024, 256 blocks — empirically best), plus:
//  - receiver setup hoisted pre-barrier (overlaps counter zeroing)
//  - phase-2 reads s_cnt and s_buck slots IN PARALLEL (speculative slot read,
//    discarded where slot >= cnt) — one LDS round trip off the critical path
//  - phase-1 bucket store unconditional into (pos & 15); overflowed cells are
//    served exclusively by the exact fallback, so wrapped slots are harmless
__global__ __launch_bounds__(TPB) void gwave_one(
    const float* __restrict__ ell, const float* __restrict__ theta,
    const float* __restrict__ fs, const float* __restrict__ mass,
    const unsigned char* __restrict__ frozen,
    const int* __restrict__ gsize_p, int n,
    float* __restrict__ out)
{
    __shared__ int s_cnt[MAXC];                    //  4 KB
    __shared__ unsigned short s_buck[MAXC][CAP];   // 32 KB (token ids)

    const float PHI       = 1.61803398875f;
    const float INV_PHI   = 0.61803398875f;
    const float ONE_P_PHI = 2.61803398875f;
    const float TAU  = 6.2831855f;                 // float32(2*pi)
    const float PI_F = 3.14159274f;                // float32(pi)
    const float EPS  = 1e-10f;

    const int tid  = threadIdx.x;
    const int lane = tid & 63;
    const int w    = tid >> 6;
    const int gs = *gsize_p;
    const int C = gs * gs;                         // <= MAXC
    const bool pow2   = (gs & (gs - 1)) == 0;
    const float mule  = (float)gs * 0.5f;          // 1/cw_ell, exact iff pow2
    const float cw_ell = 2.0f / (float)gs;
    const float cw_th  = TAU  / (float)gs;

    // cell coords (bit-exact vs reference for all inputs)
    auto cell_ce = [&](float e) -> int {
        const float q = pow2 ? e * mule : e / cw_ell;
        return min(max((int)floorf(q), 0), gs - 1);
    };
    auto cell_ct = [&](float t) -> int {
        float tw = t;
        if (!(t >= 0.f && t < TAU))                // rare path: exact floor-mod
            tw = t - floorf(t / TAU) * TAU;
        return min(max((int)floorf(tw / cw_th), 0), gs - 1);
    };

    // ---- zero counters (no barrier yet) ----
    for (int c = tid; c < C; c += TPB) s_cnt[c] = 0;

    // ---- receiver setup, hoisted pre-barrier (register-only, no LDS dep) ----
    const int i = blockIdx.x * RPB + w;            // wave-uniform receiver
    const int k    = lane / 7;                     // 0..9 (lane 63: k=9, idle)
    const int slot = lane - k * 7;                 // 0..6
    bool  act = false;
    float e_i = 0.f, t_i = 0.f, f_i = 0.f, m_i = 1.f, tp = 0.f;
    int   c_k = -1;
    if (i < n && !frozen[i]) {
        act = true;
        e_i = ell[i]; t_i = theta[i]; f_i = fs[i]; m_i = mass[i];
        tp = PI_F - t_i;
        const int ce_i = cell_ce(e_i);
        const int ct_i = cell_ct(t_i);
        if (k < 9) {
            const int kdiv = k / 3;
            const int ce = ce_i + kdiv - 1;                    // ell: no wrap
            if (ce >= 0 && ce < gs) {
                int ct = ct_i + (k - kdiv * 3) - 1;            // theta: wraps
                ct += (ct < 0)   ? gs : 0;
                ct -= (ct >= gs) ? gs : 0;
                c_k = ce * gs + ct;
            }
        }
    }
    __syncthreads();                               // counters zeroed

    // ---- Phase 1: bucket all tokens (4/thread at n=4096, vectorized) ----
    const int n4 = n >> 2;
    for (int b = tid; b < n4; b += TPB) {
        const float4 e4 = ((const float4*)ell)[b];
        const float4 t4 = ((const float4*)theta)[b];
        const uchar4 z4 = ((const uchar4*)frozen)[b];
        const float ee[4] = {e4.x, e4.y, e4.z, e4.w};
        const float tt[4] = {t4.x, t4.y, t4.z, t4.w};
        const unsigned char zz[4] = {z4.x, z4.y, z4.z, z4.w};
        #pragma unroll
        for (int m = 0; m < 4; ++m) {
            if (!zz[m]) {
                const int c = cell_ce(ee[m]) * gs + cell_ct(tt[m]);
                const int pos = atomicAdd(&s_cnt[c], 1);
                s_buck[c][pos & (CAP - 1)] = (unsigned short)((b << 2) + m);
            }
        }
    }
    for (int r = (n4 << 2) + tid; r < n; r += TPB) {          // scalar tail
        if (!frozen[r]) {
            const int c = cell_ce(ell[r]) * gs + cell_ct(theta[r]);
            const int pos = atomicAdd(&s_cnt[c], 1);
            s_buck[c][pos & (CAP - 1)] = (unsigned short)r;
        }
    }
    __syncthreads();                               // buckets ready

    // ---- Phase 2: one wave per receiver ----
    if (i >= n) return;                            // after all barriers

    float Fe = 0.f, Ft = 0.f;
    if (act) {                                     // act is wave-uniform
        // candidate chain (id != i checked by caller)
        auto chain = [&](int id) {
            const float dl = ell[id] - e_i;
            // jnp.mod(dtheta+pi, tau)-pi via predicated wrap: x in (-pi,3pi),
            // so +-TAU correction matches floor-mod bit-for-bit.
            float x = theta[id] + tp;
            x += (x < 0.f)  ? TAU : 0.f;
            x -= (x >= TAU) ? TAU : 0.f;
            const float dt = x - PI_F;
            const float inner = fpow_pos(fabsf(dl), PHI)
                              + fpow_pos(fabsf(dt), PHI);
            const float dL = fpow_pos(inner, INV_PHI) + EPS;
            const float fm = __fdividef(f_i * fs[id],
                                fpow_pos(dL, ONE_P_PHI) * m_i + EPS);
            const float ww = fm * __fdividef(1.f, dL);
            Fe += ww * dl;
            Ft += ww * dt;
        };

        // parallel LDS reads: cnt and the slot-0..6 candidate id together
        // (speculative id read is discarded where slot >= cnt)
        const bool cell_ok = (c_k >= 0);
        const int  cnt     = cell_ok ? s_cnt[c_k] : 0;
        const int  id0     = cell_ok ? s_buck[c_k][slot] : 0;   // issues with cnt
        const bool use_bucket = cell_ok && (cnt <= CAP);

        if (use_bucket && slot < cnt) {
            if (id0 != i) chain(id0);
        }
        // ballot-guarded extra passes for slots [7,14), [14,16)
        #pragma unroll
        for (int base = 7; base < CAP; base += 7) {
            const unsigned long long need =
                __ballot(use_bucket && slot == 0 && cnt > base);
            if (!need) break;                                 // wave-uniform
            const int s2 = base + slot;
            if (use_bucket && s2 < cnt) {                     // s2 < cnt <= 16
                const int id = s_buck[c_k][s2];
                if (id != i) chain(id);
            }
        }

        // exact fallback for overflowed cells (cnt > CAP): whole-cell rescan
        const unsigned long long oflow =
            __ballot(cell_ok && slot == 0 && cnt > CAP);
        if (oflow) {                                          // ~never taken
            for (int kk = 0; kk < 9; ++kk) {
                const int src  = kk * 7;
                const int cc   = __shfl(c_k, src);
                const int ccnt = __shfl(cnt, src);
                if (cc >= 0 && ccnt > CAP) {
                    for (int q = lane; q < n; q += 64) {
                        if (q != i && !frozen[q]) {
                            const int cq = cell_ce(ell[q]) * gs
                                         + cell_ct(theta[q]);
                            if (cq == cc) chain(q);
                        }
                    }
                }
            }
        }
    }

    // 64-lane butterfly reduce
    Fe += __shfl_xor(Fe, 1);
    Ft += __shfl_xor(Ft, 1);
    Fe += __shfl_xor(Fe, 2);
    Ft += __shfl_xor(Ft, 2);
    Fe += __shfl_xor(Fe, 4);
    Ft += __shfl_xor(Ft, 4);
    Fe += __shfl_xor(Fe, 8);
    Ft += __shfl_xor(Ft, 8);
    Fe += __shfl_xor(Fe, 16);
    Ft += __shfl_xor(Ft, 16);
    Fe += __shfl_xor(Fe, 32);
    Ft += __shfl_xor(Ft, 32);

    if (lane == 0) {                               // frozen receivers store 0
        out[i]     = Fe;
        out[n + i] = Ft;
    }
}

extern "C" void kernel_launch(void* const* d_in, const int* in_sizes, int n_in,
                              void* d_out, int out_size, void* d_ws, size_t ws_size,
                              hipStream_t stream) {
    const float* ell   = (const float*)d_in[0];
    const float* theta = (const float*)d_in[1];
    const float* fs    = (const float*)d_in[2];
    const float* mass  = (const float*)d_in[3];
    const unsigned char* frozen = (const unsigned char*)d_in[4];
    const int* gsize   = (const int*)d_in[5];
    float* out = (float*)d_out;
    const int n = in_sizes[0];                // assumed <= NMAX (test: 4096)

    const int blocks = (n + RPB - 1) / RPB;   // 256 at n=4096 — 1 per CU
    gwave_one<<<blocks, TPB, 0, stream>>>(
        ell, theta, fs, mass, frozen, gsize, n, out);
}